// Round 4
// baseline (3191.274 us; speedup 1.0000x reference)
//
#include <hip/hip_runtime.h>

#define BATCH 32
#define NPTS  262144
#define KSAMP 256
#define NF    10
#define INDIM 60
#define HID   768

#define NBLK_PER_B 8
#define SLICE (NPTS/NBLK_PER_B)   // 32768 points per block (one CU)
// per-thread point layout: 8 groups of 4 pts
//   j=0..3  -> registers (16 pts)
//   j=4..6  -> LDS       (12 pts, 144 KB)
//   j=7     -> global SoA (4 pts, L2-resident)
#define REG_G 4
#define LDS_G 3

#define PI_F 3.14159274101257324f  // float(math.pi)
#define PAY56 0x00FFFFFFFFFFFFFFull

typedef float v2f __attribute__((ext_vector_type(2)));

// Static device scratch (rewritten every call before use)
__device__ float g_px[BATCH*NPTS];   // only group j=7 regions used
__device__ float g_py[BATCH*NPTS];
__device__ float g_pz[BATCH*NPTS];
__device__ float g_samp[BATCH*KSAMP*3];
__device__ float g_enc[(size_t)BATCH*KSAMP*INDIM];
__device__ float g_Wt[INDIM*HID];
// [parity][slice][word]: word0=[tag|val|~idx], word1=[tag|x|y_hi24], word2=[tag|y_lo8|z|pad]
__device__ unsigned long long g_slot[BATCH][2][NBLK_PER_B][3];

__device__ __forceinline__ float san(float v){
  float m = v*0.0f;                 // finite -> 0, inf/nan -> nan (no fast-math fold)
  return (m == 0.0f) ? v : 0.0f;
}

__device__ __forceinline__ unsigned long long shfl64_xor(unsigned long long v, int m){
  unsigned lo = __shfl_xor((unsigned)v, m);
  unsigned hi = __shfl_xor((unsigned)(v>>32), m);
  return ((unsigned long long)hi<<32)|lo;
}
__device__ __forceinline__ unsigned long long shfl64(unsigned long long v, int src){
  unsigned lo = __shfl((unsigned)v, src);
  unsigned hi = __shfl((unsigned)(v>>32), src);
  return ((unsigned long long)hi<<32)|lo;
}

// ---------------- region prepass: sanitize + SoA for global-resident 1/8 ----------------
__global__ __launch_bounds__(256) void region_prepass(const float* __restrict__ pc){
  int bid = blockIdx.x;             // 1024 blocks
  int b   = bid >> 5;               // 32 blocks per batch
  int rem = bid & 31;
  int q   = rem*1024 + threadIdx.x*4;   // 0..32767 region-local (per batch)
  int s   = q >> 12;                    // slice (4096 pts of group 7 per slice)
  int o   = q & 4095;
  int p   = s*SLICE + 7*4096 + o;       // global point index in batch
  const float* src = pc + ((size_t)b*NPTS + p)*3;
  float4 A = *(const float4*)(src);
  float4 Bv= *(const float4*)(src+4);
  float4 C = *(const float4*)(src+8);
  float v[12] = {A.x,A.y,A.z,A.w,Bv.x,Bv.y,Bv.z,Bv.w,C.x,C.y,C.z,C.w};
#pragma unroll
  for (int j=0;j<12;j++) v[j] = san(v[j]);
  size_t base = (size_t)b*NPTS + p;
  *(float4*)(g_px+base) = make_float4(v[0],v[3],v[6],v[9]);
  *(float4*)(g_py+base) = make_float4(v[1],v[4],v[7],v[10]);
  *(float4*)(g_pz+base) = make_float4(v[2],v[5],v[8],v[11]);
}

// ---------------- W transpose + slot clear ----------------
__global__ __launch_bounds__(256) void wtrans(const float* __restrict__ W){
  int idx = blockIdx.x*256 + threadIdx.x;   // < 60*768 = 46080
  int d = idx / HID;
  int h = idx - d*HID;
  g_Wt[idx] = W[h*INDIM + d];
  if (blockIdx.x == 0){
    // clear all 32*2*8*3 = 1536 slot words (stale tags could alias tag==k)
#pragma unroll
    for (int r=0;r<6;r++)
      ((unsigned long long*)g_slot)[threadIdx.x + 256*r] = 0ull;
  }
}

// ---------------- FPS ----------------
__global__ __attribute__((amdgpu_flat_work_group_size(1024,1024)))
           __attribute__((amdgpu_waves_per_eu(4,4)))
void fps_kernel(const float* __restrict__ pc){
#pragma clang fp contract(off)
  // contract(off): distance chain must stay mul+add (rn each step, no FMA
  // fusion) to be bit-exact vs the reference reduction.
  __shared__ float4 sX[LDS_G*1024], sY[LDS_G*1024], sZ[LDS_G*1024];  // 144 KB
  // per-wave candidate: 3 tagged u64 words (val/idx + packed coords)
  __shared__ unsigned long long s_cand[2][16][3];

  // XCD-locality swizzle: assuming round-robin blockIdx%8 -> XCD, this puts
  // all 8 slices of a batch on ONE XCD (4 batches per XCD). Perf-only heuristic.
  const int blk = blockIdx.x;
  const int b   = (blk & 7) + 8*(blk >> 6);   // batch
  const int s   = (blk >> 3) & 7;             // slice
  const int tid = threadIdx.x;
  const int lane = tid & 63, wave = tid >> 6;
  const size_t bN = (size_t)b*NPTS;
  const int soff = s*SLICE;

  // ---- one-time load: regs (j=0..3, packed pairs) and LDS (j=4..6) ----
  v2f rx2[REG_G*2], ry2[REG_G*2], rz2[REG_G*2];   // pair p covers pts 2p,2p+1
#pragma unroll
  for (int j=0;j<REG_G+LDS_G;j++){
    int p0 = soff + j*4096 + tid*4;
    const float* src = pc + (bN + p0)*3;
    float4 A = *(const float4*)(src);
    float4 Bv= *(const float4*)(src+4);
    float4 C = *(const float4*)(src+8);
    float v[12] = {A.x,A.y,A.z,A.w,Bv.x,Bv.y,Bv.z,Bv.w,C.x,C.y,C.z,C.w};
#pragma unroll
    for (int q=0;q<12;q++) v[q] = san(v[q]);
    if (j < REG_G){
      rx2[j*2+0] = (v2f){v[0], v[3]};  rx2[j*2+1] = (v2f){v[6], v[9]};
      ry2[j*2+0] = (v2f){v[1], v[4]};  ry2[j*2+1] = (v2f){v[7], v[10]};
      rz2[j*2+0] = (v2f){v[2], v[5]};  rz2[j*2+1] = (v2f){v[8], v[11]};
    } else {
      sX[(j-REG_G)*1024+tid] = make_float4(v[0],v[3],v[6],v[9]);
      sY[(j-REG_G)*1024+tid] = make_float4(v[1],v[4],v[7],v[10]);
      sZ[(j-REG_G)*1024+tid] = make_float4(v[2],v[5],v[8],v[11]);
    }
  }

  float d[32];
#pragma unroll
  for (int i=0;i<32;i++) d[i] = __builtin_huge_valf();

  // first sample = sanitized point 0 (uniform scalar loads)
  float lx = san(pc[bN*3+0]), ly = san(pc[bN*3+1]), lz = san(pc[bN*3+2]);
  if (s==0 && tid<3) g_samp[(size_t)b*KSAMP*3 + tid] = san(pc[bN*3 + tid]);
  if (tid < 96) ((unsigned long long*)s_cand)[tid] = 0ull;
  __syncthreads();   // LDS coords + cleared candidates visible; the ONLY block barrier

  const size_t gb = bN + soff + (size_t)7*4096 + tid*4;   // loop-invariant

  for (int k=1; k<KSAMP; k++){
    const int par = k & 1;
    const unsigned long long tagk = (unsigned long long)(unsigned)k << 56;
    // issue global-group loads first (L2-resident region)
    float4 gx = *(const float4*)(g_px+gb);
    float4 gy = *(const float4*)(g_py+gb);
    float4 gz = *(const float4*)(g_pz+gb);

    // broadcast last sample into packed form
    v2f l2x = (v2f){lx,lx}, l2y = (v2f){ly,ly}, l2z = (v2f){lz,lz};

    float bestv = -1.0f; int bestc = 0;
    float bx = 0.0f, by = 0.0f, bz = 0.0f;   // coords of best (tracked inline)

    // packed distance for a PAIR of points (codes DI, DI+1); scalar tracking in
    // ascending index order preserves the first-max tie-break. pk ops are IEEE
    // rn per half == bit-exact vs the scalar __f*_rn chain.
#define UPD2(X2,Y2,Z2, DI) { \
      v2f dx_ = (X2) - l2x, dy_ = (Y2) - l2y, dz_ = (Z2) - l2z; \
      v2f dd_ = ((dx_*dx_) + (dy_*dy_)) + (dz_*dz_); \
      float nd0_ = fminf(d[DI], dd_.x);  d[DI] = nd0_; \
      if (nd0_ > bestv){ bestv = nd0_; bestc = (DI); bx=(X2).x; by=(Y2).x; bz=(Z2).x; } \
      float nd1_ = fminf(d[(DI)+1], dd_.y);  d[(DI)+1] = nd1_; \
      if (nd1_ > bestv){ bestv = nd1_; bestc = (DI)+1; bx=(X2).y; by=(Y2).y; bz=(Z2).y; } }

    // register groups j=0..3 (codes 0..15)
#pragma unroll
    for (int p=0;p<REG_G*2;p++)
      UPD2(rx2[p], ry2[p], rz2[p], p*2)
    // LDS groups j=4..6 (codes 16..27)
#pragma unroll
    for (int j=0;j<LDS_G;j++){
      float4 X = sX[j*1024+tid], Y = sY[j*1024+tid], Z = sZ[j*1024+tid];
      v2f Xa=(v2f){X.x,X.y}, Xb=(v2f){X.z,X.w};
      v2f Ya=(v2f){Y.x,Y.y}, Yb=(v2f){Y.z,Y.w};
      v2f Za=(v2f){Z.x,Z.y}, Zb=(v2f){Z.z,Z.w};
      UPD2(Xa, Ya, Za, (REG_G+j)*4)
      UPD2(Xb, Yb, Zb, (REG_G+j)*4+2)
    }
    // global group j=7 (codes 28..31)
    {
      v2f Xa=(v2f){gx.x,gx.y}, Xb=(v2f){gx.z,gx.w};
      v2f Ya=(v2f){gy.x,gy.y}, Yb=(v2f){gy.z,gy.w};
      v2f Za=(v2f){gz.x,gz.y}, Zb=(v2f){gz.z,gz.w};
      UPD2(Xa, Ya, Za, 28)
      UPD2(Xb, Yb, Zb, 30)
    }
#undef UPD2

    // code -> batch-local index (scan order was ascending-index)
    int besti = soff + ((bestc>>2)<<12) + (tid<<2) + (bestc&3);
    // key: [val:32][0xFFFFFF^idx:24] — u64 max == (max val, then smallest idx);
    // idx unique => keys unique => winner selection by equality is well-defined.
    unsigned long long key = ((unsigned long long)__float_as_uint(bestv) << 24)
                           | (unsigned long long)(0xFFFFFFu ^ (unsigned)besti);

    // intra-wave argmax butterfly, coords ride along
#pragma unroll
    for (int m=1; m<64; m<<=1){
      unsigned long long ok = shfl64_xor(key, m);
      float ox=__shfl_xor(bx,m), oy=__shfl_xor(by,m), oz=__shfl_xor(bz,m);
      if (ok > key){ key=ok; bx=ox; by=oy; bz=oz; }
    }
    // per-wave candidate publish: 3 self-contained tagged u64 words
    if (lane==0){
      unsigned xb=__float_as_uint(bx), yb=__float_as_uint(by), zb=__float_as_uint(bz);
      unsigned long long w0 = tagk | key;
      unsigned long long w1 = tagk | ((unsigned long long)xb<<24) | (yb>>8);
      unsigned long long w2 = tagk | ((unsigned long long)(yb&0xFFu)<<48)
                                   | ((unsigned long long)zb<<16);
      __hip_atomic_store(&s_cand[par][wave][0], w0, __ATOMIC_RELAXED, __HIP_MEMORY_SCOPE_WORKGROUP);
      __hip_atomic_store(&s_cand[par][wave][1], w1, __ATOMIC_RELAXED, __HIP_MEMORY_SCOPE_WORKGROUP);
      __hip_atomic_store(&s_cand[par][wave][2], w2, __ATOMIC_RELAXED, __HIP_MEMORY_SCOPE_WORKGROUP);
    }

    // wave0: gather 16 wave candidates (48 tagged words polled in parallel),
    // reduce, publish block candidate (3 tagged words) to the global slot.
    if (wave==0){
      unsigned long long pay = 0;
      if (lane < 48){
        int wv = lane & 15, word = lane >> 4;
        unsigned long long v;
        for (;;){
          v = __hip_atomic_load(&s_cand[par][wv][word], __ATOMIC_RELAXED, __HIP_MEMORY_SCOPE_WORKGROUP);
          if ((unsigned)(v >> 56) == (unsigned)k) break;
          __builtin_amdgcn_s_sleep(1);
        }
        pay = v & PAY56;
      }
      __builtin_amdgcn_s_setprio(1);
      unsigned long long bk = pay;   // lanes 0..15: keys; butterfly within 16-groups
#pragma unroll
      for (int m=1; m<16; m<<=1){
        unsigned long long o = shfl64_xor(bk, m);
        if (o > bk) bk = o;
      }
      unsigned long long wink = shfl64(bk, 0);
      unsigned long long bal = __ballot(lane<16 && pay==wink);
      int wv = (int)__ffsll((long long)bal) - 1;      // winning wave
      // per-lane partial decodes, then pull the winner's via shuffle
      unsigned xb =(unsigned)(pay>>24), yh =(unsigned)(pay & 0xFFFFFFu);   // w1 lanes 16..31
      unsigned yl =(unsigned)((pay>>48)&0xFFu), zb =(unsigned)(pay>>16);   // w2 lanes 32..47
      unsigned x_b = __shfl(xb, 16+wv);
      unsigned y_hi= __shfl(yh, 16+wv);
      unsigned y_lo= __shfl(yl, 32+wv);
      unsigned z_b = __shfl(zb, 32+wv);
      unsigned long long w0g = tagk | wink;
      unsigned long long w1g = tagk | ((unsigned long long)x_b<<24) | y_hi;
      unsigned long long w2g = tagk | ((unsigned long long)y_lo<<48)
                                    | ((unsigned long long)z_b<<16);
      unsigned long long myw = (lane==0) ? w0g : ((lane==1) ? w1g : w2g);
      if (lane < 3)
        __hip_atomic_store(&g_slot[b][par][s][lane], myw, __ATOMIC_RELAXED, __HIP_MEMORY_SCOPE_AGENT);
      __builtin_amdgcn_s_setprio(0);
    }

    // EVERY wave polls the 8 slices' 3 words itself (24 lanes in parallel) —
    // no LDS flag/s_res hop, no coordinate memory fetch; waves resume the
    // instant the last slice lands. s_sleep keeps spins off the issue slots.
    unsigned long long gpay = 0;
    if (lane < 24){
      int sl = lane & 7, word = lane >> 3;
      unsigned long long gv;
      for (;;){
        gv = __hip_atomic_load(&g_slot[b][par][sl][word], __ATOMIC_RELAXED, __HIP_MEMORY_SCOPE_AGENT);
        if ((unsigned)(gv >> 56) == (unsigned)k) break;
        __builtin_amdgcn_s_sleep(1);
      }
      gpay = gv & PAY56;
    }
    unsigned long long gk = gpay;   // lanes 0..7: keys; butterfly within 8-groups
#pragma unroll
    for (int m=1; m<8; m<<=1){
      unsigned long long o = shfl64_xor(gk, m);
      if (o > gk) gk = o;
    }
    unsigned long long wing = shfl64(gk, 0);
    unsigned long long gbal = __ballot(lane<8 && gpay==wing);
    int ws = (int)__ffsll((long long)gbal) - 1;       // winning slice
    unsigned xb2=(unsigned)(gpay>>24), yh2=(unsigned)(gpay & 0xFFFFFFu);  // w1 lanes 8..15
    unsigned yl2=(unsigned)((gpay>>48)&0xFFu), zb2=(unsigned)(gpay>>16);  // w2 lanes 16..23
    unsigned X  = __shfl(xb2,  8+ws);
    unsigned YH = __shfl(yh2,  8+ws);
    unsigned YL = __shfl(yl2, 16+ws);
    unsigned Z  = __shfl(zb2, 16+ws);
    lx = __uint_as_float(X);
    ly = __uint_as_float((YH<<8) | YL);
    lz = __uint_as_float(Z);
    if (s==0 && wave==0 && lane<3){
      float cv = (lane==0) ? lx : ((lane==1) ? ly : lz);
      g_samp[((size_t)b*KSAMP + k)*3 + lane] = cv;
    }
  }
}

// ---------------- normalize + Fourier encode ----------------
template<int OP>  // 0 sum, 1 max, 2 min
__device__ __forceinline__ float blk_red(float v, float* s4){
  int tid = threadIdx.x;
#pragma unroll
  for (int off=32; off; off>>=1){
    float o = __shfl_down(v, off);
    v = (OP==0) ? v+o : ((OP==1) ? fmaxf(v,o) : fminf(v,o));
  }
  if ((tid&63)==0) s4[tid>>6] = v;
  __syncthreads();
  float r0=s4[0], r1=s4[1], r2=s4[2], r3=s4[3];
  float r = (OP==0) ? ((r0+r1)+(r2+r3))
          : ((OP==1) ? fmaxf(fmaxf(r0,r1),fmaxf(r2,r3))
                     : fminf(fminf(r0,r1),fminf(r2,r3)));
  __syncthreads();
  return r;
}

__global__ __launch_bounds__(256) void norm_encode(){
  __shared__ float s4[4];
  int b = blockIdx.x, k = threadIdx.x;
  const float* sp = &g_samp[((size_t)b*KSAMP + k)*3];
  float x = sp[0], y = sp[1], z = sp[2];

  float cx = blk_red<0>(x, s4) * (1.0f/KSAMP);
  float cy = blk_red<0>(y, s4) * (1.0f/KSAMP);
  float cz = blk_red<0>(z, s4) * (1.0f/KSAMP);

  float ux = __fsub_rn(x,cx), uy = __fsub_rn(y,cy), uz = __fsub_rn(z,cz);

  float mxx = blk_red<1>(ux, s4), mnx = blk_red<2>(ux, s4);
  float mxy = blk_red<1>(uy, s4), mny = blk_red<2>(uy, s4);
  float mxz = blk_red<1>(uz, s4), mnz = blk_red<2>(uz, s4);
  float bx = __fsub_rn(mxx,mnx), by = __fsub_rn(mxy,mny), bz = __fsub_rn(mxz,mnz);
  float md = fmaxf(fmaxf(bx,by),bz);
  float scale = (md > 1e-8f) ? md : 1.0f;

  float n3[3] = { __fdiv_rn(ux,scale), __fdiv_rn(uy,scale), __fdiv_rn(uz,scale) };

  float* e = &g_enc[((size_t)b*KSAMP + k)*INDIM];
#pragma unroll
  for (int c=0;c<3;c++){
    float base = n3[c];
#pragma unroll
    for (int f=0; f<NF; f++){
      float t = __fmul_rn(base, (float)(1<<f));
      float a = __fmul_rn(t, PI_F);
      e[c*2*NF + f*2 + 0] = sinf(a);
      e[c*2*NF + f*2 + 1] = cosf(a);
    }
  }
}

// ---------------- GEMM ----------------
__global__ __launch_bounds__(256) void gemm_kernel(const float* __restrict__ bias,
                                                   float* __restrict__ out){
  __shared__ float s_enc[4*INDIM];
  int blk = blockIdx.x, tid = threadIdx.x;
  int row0 = blk*4;                         // 4 (b,k) rows per block
  if (tid < 4*INDIM) s_enc[tid] = g_enc[(size_t)row0*INDIM + tid];
  __syncthreads();

  float acc[4][3] = {};
  for (int d=0; d<INDIM; d++){
    float w0 = g_Wt[d*HID + tid];
    float w1 = g_Wt[d*HID + tid + 256];
    float w2 = g_Wt[d*HID + tid + 512];
#pragma unroll
    for (int r=0;r<4;r++){
      float ev = s_enc[r*INDIM + d];
      acc[r][0] = fmaf(ev, w0, acc[r][0]);
      acc[r][1] = fmaf(ev, w1, acc[r][1]);
      acc[r][2] = fmaf(ev, w2, acc[r][2]);
    }
  }
  float b0=bias[tid], b1=bias[tid+256], b2=bias[tid+512];
#pragma unroll
  for (int r=0;r<4;r++){
    size_t o = (size_t)(row0+r)*HID;
    out[o+tid]     = acc[r][0]+b0;
    out[o+tid+256] = acc[r][1]+b1;
    out[o+tid+512] = acc[r][2]+b2;
  }
}

// ---------------- launch ----------------
extern "C" void kernel_launch(void* const* d_in, const int* in_sizes, int n_in,
                              void* d_out, int out_size, void* d_ws, size_t ws_size,
                              hipStream_t stream){
  const float* pc   = (const float*)d_in[0];
  const float* W    = (const float*)d_in[1];
  const float* bias = (const float*)d_in[2];
  float* out = (float*)d_out;

  region_prepass<<<1024, 256, 0, stream>>>(pc);
  wtrans        <<<(INDIM*HID)/256, 256, 0, stream>>>(W);

  void* args[] = { (void*)&pc };
  hipLaunchCooperativeKernel((void*)fps_kernel, dim3(BATCH*NBLK_PER_B), dim3(1024),
                             args, 0, stream);

  norm_encode<<<BATCH, KSAMP, 0, stream>>>();
  gemm_kernel<<<(BATCH*KSAMP)/4, 256, 0, stream>>>(bias, out);
}

// Round 5
// 2818.486 us; speedup vs baseline: 1.1323x; 1.1323x over previous
//
#include <hip/hip_runtime.h>

#define BATCH 32
#define NPTS  262144
#define KSAMP 256
#define NF    10
#define INDIM 60
#define HID   768

#define NBLK_PER_B 8
#define SLICE (NPTS/NBLK_PER_B)   // 32768 points per block (one CU)
// per-thread point layout: 8 groups of 4 pts
//   j=0..3  -> registers (16 pts)
//   j=4..6  -> LDS       (12 pts, 144 KB)
//   j=7     -> global SoA (4 pts, L2-resident)
#define REG_G 4
#define LDS_G 3

#define PI_F 3.14159274101257324f  // float(math.pi)
#define PAY56 0x00FFFFFFFFFFFFFFull

typedef float v2f __attribute__((ext_vector_type(2)));

// Static device scratch (rewritten every call before use)
__device__ float g_px[BATCH*NPTS];   // only group j=7 regions used
__device__ float g_py[BATCH*NPTS];
__device__ float g_pz[BATCH*NPTS];
__device__ float g_samp[BATCH*KSAMP*3];
__device__ float g_enc[(size_t)BATCH*KSAMP*INDIM];
__device__ float g_Wt[INDIM*HID];
// [parity][slice][word]: word0=[tag|val|~idx], word1=[tag|x|y_hi24], word2=[tag|y_lo8|z|pad]
__device__ unsigned long long g_slot[BATCH][2][NBLK_PER_B][3];

__device__ __forceinline__ float san(float v){
  float m = v*0.0f;                 // finite -> 0, inf/nan -> nan (no fast-math fold)
  return (m == 0.0f) ? v : 0.0f;
}

__device__ __forceinline__ unsigned long long shfl64_xor(unsigned long long v, int m){
  unsigned lo = __shfl_xor((unsigned)v, m);
  unsigned hi = __shfl_xor((unsigned)(v>>32), m);
  return ((unsigned long long)hi<<32)|lo;
}
__device__ __forceinline__ unsigned long long shfl64(unsigned long long v, int src){
  unsigned lo = __shfl((unsigned)v, src);
  unsigned hi = __shfl((unsigned)(v>>32), src);
  return ((unsigned long long)hi<<32)|lo;
}

// ---------------- region prepass: sanitize + SoA for global-resident 1/8 ----------------
__global__ __launch_bounds__(256) void region_prepass(const float* __restrict__ pc){
  int bid = blockIdx.x;             // 1024 blocks
  int b   = bid >> 5;               // 32 blocks per batch
  int rem = bid & 31;
  int q   = rem*1024 + threadIdx.x*4;   // 0..32767 region-local (per batch)
  int s   = q >> 12;                    // slice (4096 pts of group 7 per slice)
  int o   = q & 4095;
  int p   = s*SLICE + 7*4096 + o;       // global point index in batch
  const float* src = pc + ((size_t)b*NPTS + p)*3;
  float4 A = *(const float4*)(src);
  float4 Bv= *(const float4*)(src+4);
  float4 C = *(const float4*)(src+8);
  float v[12] = {A.x,A.y,A.z,A.w,Bv.x,Bv.y,Bv.z,Bv.w,C.x,C.y,C.z,C.w};
#pragma unroll
  for (int j=0;j<12;j++) v[j] = san(v[j]);
  size_t base = (size_t)b*NPTS + p;
  *(float4*)(g_px+base) = make_float4(v[0],v[3],v[6],v[9]);
  *(float4*)(g_py+base) = make_float4(v[1],v[4],v[7],v[10]);
  *(float4*)(g_pz+base) = make_float4(v[2],v[5],v[8],v[11]);
}

// ---------------- W transpose + slot clear ----------------
__global__ __launch_bounds__(256) void wtrans(const float* __restrict__ W){
  int idx = blockIdx.x*256 + threadIdx.x;   // < 60*768 = 46080
  int d = idx / HID;
  int h = idx - d*HID;
  g_Wt[idx] = W[h*INDIM + d];
  if (blockIdx.x == 0){
    // clear all 32*2*8*3 = 1536 slot words (stale tags could alias tag==k)
#pragma unroll
    for (int r=0;r<6;r++)
      ((unsigned long long*)g_slot)[threadIdx.x + 256*r] = 0ull;
  }
}

// ---------------- FPS ----------------
__global__ __attribute__((amdgpu_flat_work_group_size(1024,1024)))
           __attribute__((amdgpu_waves_per_eu(4,4)))
void fps_kernel(const float* __restrict__ pc){
#pragma clang fp contract(off)
  // contract(off): distance chain must stay mul+add (rn each step, no FMA
  // fusion) to be bit-exact vs the reference reduction.
  __shared__ float4 sX[LDS_G*1024], sY[LDS_G*1024], sZ[LDS_G*1024];  // 144 KB
  // per-wave candidate: 3 tagged u64 words (val/idx + packed coords)
  __shared__ unsigned long long s_cand[2][16][3];
  __shared__ float s_res[2][4];                 // winner coords (parity dbuf)
  __shared__ int   s_flag[2];                   // iteration-complete flag

  // XCD-locality swizzle: assuming round-robin blockIdx%8 -> XCD, this puts
  // all 8 slices of a batch on ONE XCD (4 batches per XCD). Perf-only heuristic.
  const int blk = blockIdx.x;
  const int b   = (blk & 7) + 8*(blk >> 6);   // batch
  const int s   = (blk >> 3) & 7;             // slice
  const int tid = threadIdx.x;
  const int lane = tid & 63, wave = tid >> 6;
  const size_t bN = (size_t)b*NPTS;
  const int soff = s*SLICE;

  // ---- one-time load: regs (j=0..3, packed pairs) and LDS (j=4..6) ----
  v2f rx2[REG_G*2], ry2[REG_G*2], rz2[REG_G*2];   // pair p covers pts 2p,2p+1
#pragma unroll
  for (int j=0;j<REG_G+LDS_G;j++){
    int p0 = soff + j*4096 + tid*4;
    const float* src = pc + (bN + p0)*3;
    float4 A = *(const float4*)(src);
    float4 Bv= *(const float4*)(src+4);
    float4 C = *(const float4*)(src+8);
    float v[12] = {A.x,A.y,A.z,A.w,Bv.x,Bv.y,Bv.z,Bv.w,C.x,C.y,C.z,C.w};
#pragma unroll
    for (int q=0;q<12;q++) v[q] = san(v[q]);
    if (j < REG_G){
      rx2[j*2+0] = (v2f){v[0], v[3]};  rx2[j*2+1] = (v2f){v[6], v[9]};
      ry2[j*2+0] = (v2f){v[1], v[4]};  ry2[j*2+1] = (v2f){v[7], v[10]};
      rz2[j*2+0] = (v2f){v[2], v[5]};  rz2[j*2+1] = (v2f){v[8], v[11]};
    } else {
      sX[(j-REG_G)*1024+tid] = make_float4(v[0],v[3],v[6],v[9]);
      sY[(j-REG_G)*1024+tid] = make_float4(v[1],v[4],v[7],v[10]);
      sZ[(j-REG_G)*1024+tid] = make_float4(v[2],v[5],v[8],v[11]);
    }
  }

  float d[32];
#pragma unroll
  for (int i=0;i<32;i++) d[i] = __builtin_huge_valf();

  // first sample = sanitized point 0 (uniform scalar loads)
  float lx = san(pc[bN*3+0]), ly = san(pc[bN*3+1]), lz = san(pc[bN*3+2]);
  if (s==0 && tid<3) g_samp[(size_t)b*KSAMP*3 + tid] = san(pc[bN*3 + tid]);
  if (tid==0){ s_flag[0]=0; s_flag[1]=0; }
  if (tid < 96) ((unsigned long long*)s_cand)[tid] = 0ull;
  __syncthreads();   // LDS coords + cleared候 flags visible; the ONLY block barrier

  const size_t gb = bN + soff + (size_t)7*4096 + tid*4;   // loop-invariant

  for (int k=1; k<KSAMP; k++){
    const int par = k & 1;
    const unsigned long long tagk = (unsigned long long)(unsigned)k << 56;
    // issue global-group loads first (L2-resident region)
    float4 gx = *(const float4*)(g_px+gb);
    float4 gy = *(const float4*)(g_py+gb);
    float4 gz = *(const float4*)(g_pz+gb);

    // broadcast last sample into packed form
    v2f l2x = (v2f){lx,lx}, l2y = (v2f){ly,ly}, l2z = (v2f){lz,lz};

    float bestv = -1.0f; int bestc = 0;
    float bx = 0.0f, by = 0.0f, bz = 0.0f;   // coords of best (tracked inline)

    // packed distance for a PAIR of points (codes DI, DI+1); scalar tracking in
    // ascending index order preserves the first-max tie-break. pk ops are IEEE
    // rn per half == bit-exact vs the scalar __f*_rn chain.
#define UPD2(X2,Y2,Z2, DI) { \
      v2f dx_ = (X2) - l2x, dy_ = (Y2) - l2y, dz_ = (Z2) - l2z; \
      v2f dd_ = ((dx_*dx_) + (dy_*dy_)) + (dz_*dz_); \
      float nd0_ = fminf(d[DI], dd_.x);  d[DI] = nd0_; \
      if (nd0_ > bestv){ bestv = nd0_; bestc = (DI); bx=(X2).x; by=(Y2).x; bz=(Z2).x; } \
      float nd1_ = fminf(d[(DI)+1], dd_.y);  d[(DI)+1] = nd1_; \
      if (nd1_ > bestv){ bestv = nd1_; bestc = (DI)+1; bx=(X2).y; by=(Y2).y; bz=(Z2).y; } }

    // register groups j=0..3 (codes 0..15)
#pragma unroll
    for (int p=0;p<REG_G*2;p++)
      UPD2(rx2[p], ry2[p], rz2[p], p*2)
    // LDS groups j=4..6 (codes 16..27)
#pragma unroll
    for (int j=0;j<LDS_G;j++){
      float4 X = sX[j*1024+tid], Y = sY[j*1024+tid], Z = sZ[j*1024+tid];
      v2f Xa=(v2f){X.x,X.y}, Xb=(v2f){X.z,X.w};
      v2f Ya=(v2f){Y.x,Y.y}, Yb=(v2f){Y.z,Y.w};
      v2f Za=(v2f){Z.x,Z.y}, Zb=(v2f){Z.z,Z.w};
      UPD2(Xa, Ya, Za, (REG_G+j)*4)
      UPD2(Xb, Yb, Zb, (REG_G+j)*4+2)
    }
    // global group j=7 (codes 28..31)
    {
      v2f Xa=(v2f){gx.x,gx.y}, Xb=(v2f){gx.z,gx.w};
      v2f Ya=(v2f){gy.x,gy.y}, Yb=(v2f){gy.z,gy.w};
      v2f Za=(v2f){gz.x,gz.y}, Zb=(v2f){gz.z,gz.w};
      UPD2(Xa, Ya, Za, 28)
      UPD2(Xb, Yb, Zb, 30)
    }
#undef UPD2

    // code -> batch-local index (scan order was ascending-index)
    int besti = soff + ((bestc>>2)<<12) + (tid<<2) + (bestc&3);
    // key: [val:32][0xFFFFFF^idx:24] — u64 max == (max val, then smallest idx);
    // idx unique => keys unique => winner selection by equality is well-defined.
    unsigned long long key = ((unsigned long long)__float_as_uint(bestv) << 24)
                           | (unsigned long long)(0xFFFFFFu ^ (unsigned)besti);

    // intra-wave argmax butterfly, coords ride along
#pragma unroll
    for (int m=1; m<64; m<<=1){
      unsigned long long ok = shfl64_xor(key, m);
      float ox=__shfl_xor(bx,m), oy=__shfl_xor(by,m), oz=__shfl_xor(bz,m);
      if (ok > key){ key=ok; bx=ox; by=oy; bz=oz; }
    }
    // per-wave candidate publish: 3 self-contained tagged u64 words
    if (lane==0){
      unsigned xb=__float_as_uint(bx), yb=__float_as_uint(by), zb=__float_as_uint(bz);
      unsigned long long w0 = tagk | key;
      unsigned long long w1 = tagk | ((unsigned long long)xb<<24) | (yb>>8);
      unsigned long long w2 = tagk | ((unsigned long long)(yb&0xFFu)<<48)
                                   | ((unsigned long long)zb<<16);
      __hip_atomic_store(&s_cand[par][wave][0], w0, __ATOMIC_RELAXED, __HIP_MEMORY_SCOPE_WORKGROUP);
      __hip_atomic_store(&s_cand[par][wave][1], w1, __ATOMIC_RELAXED, __HIP_MEMORY_SCOPE_WORKGROUP);
      __hip_atomic_store(&s_cand[par][wave][2], w2, __ATOMIC_RELAXED, __HIP_MEMORY_SCOPE_WORKGROUP);
    }

    if (wave==0){
      // gather 16 wave candidates: 48 tagged LDS words polled in parallel.
      // s_sleep: the other 15 waves are still computing — stay off their slots.
      unsigned long long pay = 0;
      if (lane < 48){
        int wv = lane & 15, word = lane >> 4;
        unsigned long long v;
        for (;;){
          v = __hip_atomic_load(&s_cand[par][wv][word], __ATOMIC_RELAXED, __HIP_MEMORY_SCOPE_WORKGROUP);
          if ((unsigned)(v >> 56) == (unsigned)k) break;
          __builtin_amdgcn_s_sleep(1);
        }
        pay = v & PAY56;
      }
      __builtin_amdgcn_s_setprio(1);
      unsigned long long bk = pay;   // lanes 0..15: keys; butterfly within 16-groups
#pragma unroll
      for (int m=1; m<16; m<<=1){
        unsigned long long o = shfl64_xor(bk, m);
        if (o > bk) bk = o;
      }
      unsigned long long wink = shfl64(bk, 0);
      unsigned long long bal = __ballot(lane<16 && pay==wink);
      int wv = (int)__ffsll((long long)bal) - 1;      // winning wave
      // per-lane partial decodes, then pull the winner's via shuffle
      unsigned xb =(unsigned)(pay>>24), yh =(unsigned)(pay & 0xFFFFFFu);   // w1 lanes 16..31
      unsigned yl =(unsigned)((pay>>48)&0xFFu), zb =(unsigned)(pay>>16);   // w2 lanes 32..47
      unsigned x_b = __shfl(xb, 16+wv);
      unsigned y_hi= __shfl(yh, 16+wv);
      unsigned y_lo= __shfl(yl, 32+wv);
      unsigned z_b = __shfl(zb, 32+wv);
      // publish block candidate (3 tagged words) to the global slot
      unsigned long long w0g = tagk | wink;
      unsigned long long w1g = tagk | ((unsigned long long)x_b<<24) | y_hi;
      unsigned long long w2g = tagk | ((unsigned long long)y_lo<<48)
                                    | ((unsigned long long)z_b<<16);
      unsigned long long myw = (lane==0) ? w0g : ((lane==1) ? w1g : w2g);
      if (lane < 3)
        __hip_atomic_store(&g_slot[b][par][s][lane], myw, __ATOMIC_RELAXED, __HIP_MEMORY_SCOPE_AGENT);

      // ONLY wave0 polls the remote slots (round-4 lesson: 16 waves polling
      // LLC lines = 7.75 GB of fetch traffic; one wave = ~0.1 GB).
      unsigned long long gpay = 0;
      if (lane < 24){
        int sl = lane & 7, word = lane >> 3;
        unsigned long long gv;
        for (;;){
          gv = __hip_atomic_load(&g_slot[b][par][sl][word], __ATOMIC_RELAXED, __HIP_MEMORY_SCOPE_AGENT);
          if ((unsigned)(gv >> 56) == (unsigned)k) break;
          __builtin_amdgcn_s_sleep(1);
        }
        gpay = gv & PAY56;
      }
      unsigned long long gk2 = gpay;   // lanes 0..7: keys; butterfly within 8-groups
#pragma unroll
      for (int m=1; m<8; m<<=1){
        unsigned long long o = shfl64_xor(gk2, m);
        if (o > gk2) gk2 = o;
      }
      unsigned long long wing = shfl64(gk2, 0);
      unsigned long long gbal = __ballot(lane<8 && gpay==wing);
      int ws = (int)__ffsll((long long)gbal) - 1;       // winning slice
      unsigned xb2=(unsigned)(gpay>>24), yh2=(unsigned)(gpay & 0xFFFFFFu);  // w1 lanes 8..15
      unsigned yl2=(unsigned)((gpay>>48)&0xFFu), zb2=(unsigned)(gpay>>16);  // w2 lanes 16..23
      unsigned X  = __shfl(xb2,  8+ws);
      unsigned YH = __shfl(yh2,  8+ws);
      unsigned YL = __shfl(yl2, 16+ws);
      unsigned Z  = __shfl(zb2, 16+ws);
      lx = __uint_as_float(X);
      ly = __uint_as_float((YH<<8) | YL);
      lz = __uint_as_float(Z);
      // broadcast to the other 15 waves via LDS (coords decoded in-register —
      // the winner-coordinate memory fetch is GONE from the serial chain)
      if (lane < 3)
        s_res[par][lane] = (lane==0) ? lx : ((lane==1) ? ly : lz);
      // release: s_res writes ordered before flag (workgroup scope)
      if (lane==0)
        __hip_atomic_store(&s_flag[par], k, __ATOMIC_RELEASE, __HIP_MEMORY_SCOPE_WORKGROUP);
      __builtin_amdgcn_s_setprio(0);
      // off-chain: record the sample (followers don't read g_samp)
      if (s==0 && lane<3){
        float cv = (lane==0) ? lx : ((lane==1) ? ly : lz);
        g_samp[((size_t)b*KSAMP + k)*3 + lane] = cv;
      }
    } else {
      // data-driven wait; s_sleep keeps the spin off the issue slots.
      while (__hip_atomic_load(&s_flag[par], __ATOMIC_ACQUIRE, __HIP_MEMORY_SCOPE_WORKGROUP) != k)
        __builtin_amdgcn_s_sleep(1);
      lx = s_res[par][0]; ly = s_res[par][1]; lz = s_res[par][2];
    }
  }
}

// ---------------- normalize + Fourier encode ----------------
template<int OP>  // 0 sum, 1 max, 2 min
__device__ __forceinline__ float blk_red(float v, float* s4){
  int tid = threadIdx.x;
#pragma unroll
  for (int off=32; off; off>>=1){
    float o = __shfl_down(v, off);
    v = (OP==0) ? v+o : ((OP==1) ? fmaxf(v,o) : fminf(v,o));
  }
  if ((tid&63)==0) s4[tid>>6] = v;
  __syncthreads();
  float r0=s4[0], r1=s4[1], r2=s4[2], r3=s4[3];
  float r = (OP==0) ? ((r0+r1)+(r2+r3))
          : ((OP==1) ? fmaxf(fmaxf(r0,r1),fmaxf(r2,r3))
                     : fminf(fminf(r0,r1),fminf(r2,r3)));
  __syncthreads();
  return r;
}

__global__ __launch_bounds__(256) void norm_encode(){
  __shared__ float s4[4];
  int b = blockIdx.x, k = threadIdx.x;
  const float* sp = &g_samp[((size_t)b*KSAMP + k)*3];
  float x = sp[0], y = sp[1], z = sp[2];

  float cx = blk_red<0>(x, s4) * (1.0f/KSAMP);
  float cy = blk_red<0>(y, s4) * (1.0f/KSAMP);
  float cz = blk_red<0>(z, s4) * (1.0f/KSAMP);

  float ux = __fsub_rn(x,cx), uy = __fsub_rn(y,cy), uz = __fsub_rn(z,cz);

  float mxx = blk_red<1>(ux, s4), mnx = blk_red<2>(ux, s4);
  float mxy = blk_red<1>(uy, s4), mny = blk_red<2>(uy, s4);
  float mxz = blk_red<1>(uz, s4), mnz = blk_red<2>(uz, s4);
  float bx = __fsub_rn(mxx,mnx), by = __fsub_rn(mxy,mny), bz = __fsub_rn(mxz,mnz);
  float md = fmaxf(fmaxf(bx,by),bz);
  float scale = (md > 1e-8f) ? md : 1.0f;

  float n3[3] = { __fdiv_rn(ux,scale), __fdiv_rn(uy,scale), __fdiv_rn(uz,scale) };

  float* e = &g_enc[((size_t)b*KSAMP + k)*INDIM];
#pragma unroll
  for (int c=0;c<3;c++){
    float base = n3[c];
#pragma unroll
    for (int f=0; f<NF; f++){
      float t = __fmul_rn(base, (float)(1<<f));
      float a = __fmul_rn(t, PI_F);
      e[c*2*NF + f*2 + 0] = sinf(a);
      e[c*2*NF + f*2 + 1] = cosf(a);
    }
  }
}

// ---------------- GEMM ----------------
__global__ __launch_bounds__(256) void gemm_kernel(const float* __restrict__ bias,
                                                   float* __restrict__ out){
  __shared__ float s_enc[4*INDIM];
  int blk = blockIdx.x, tid = threadIdx.x;
  int row0 = blk*4;                         // 4 (b,k) rows per block
  if (tid < 4*INDIM) s_enc[tid] = g_enc[(size_t)row0*INDIM + tid];
  __syncthreads();

  float acc[4][3] = {};
  for (int d=0; d<INDIM; d++){
    float w0 = g_Wt[d*HID + tid];
    float w1 = g_Wt[d*HID + tid + 256];
    float w2 = g_Wt[d*HID + tid + 512];
#pragma unroll
    for (int r=0;r<4;r++){
      float ev = s_enc[r*INDIM + d];
      acc[r][0] = fmaf(ev, w0, acc[r][0]);
      acc[r][1] = fmaf(ev, w1, acc[r][1]);
      acc[r][2] = fmaf(ev, w2, acc[r][2]);
    }
  }
  float b0=bias[tid], b1=bias[tid+256], b2=bias[tid+512];
#pragma unroll
  for (int r=0;r<4;r++){
    size_t o = (size_t)(row0+r)*HID;
    out[o+tid]     = acc[r][0]+b0;
    out[o+tid+256] = acc[r][1]+b1;
    out[o+tid+512] = acc[r][2]+b2;
  }
}

// ---------------- launch ----------------
extern "C" void kernel_launch(void* const* d_in, const int* in_sizes, int n_in,
                              void* d_out, int out_size, void* d_ws, size_t ws_size,
                              hipStream_t stream){
  const float* pc   = (const float*)d_in[0];
  const float* W    = (const float*)d_in[1];
  const float* bias = (const float*)d_in[2];
  float* out = (float*)d_out;

  region_prepass<<<1024, 256, 0, stream>>>(pc);
  wtrans        <<<(INDIM*HID)/256, 256, 0, stream>>>(W);

  void* args[] = { (void*)&pc };
  hipLaunchCooperativeKernel((void*)fps_kernel, dim3(BATCH*NBLK_PER_B), dim3(1024),
                             args, 0, stream);

  norm_encode<<<BATCH, KSAMP, 0, stream>>>();
  gemm_kernel<<<(BATCH*KSAMP)/4, 256, 0, stream>>>(bias, out);
}

// Round 6
// 1330.135 us; speedup vs baseline: 2.3992x; 2.1189x over previous
//
#include <hip/hip_runtime.h>

#define BATCH 32
#define NPTS  262144
#define KSAMP 256
#define NF    10
#define INDIM 60
#define HID   768

#define NBLK_PER_B 8
#define SLICE (NPTS/NBLK_PER_B)   // 32768 points per block (one CU)
// per-thread point layout: 8 groups of 4 pts
//   j=0..3  -> registers (16 pts)
//   j=4..6  -> LDS       (12 pts, 144 KB)
//   j=7     -> global SoA (4 pts, L2-resident)
#define REG_G 4
#define LDS_G 3

#define PI_F 3.14159274101257324f  // float(math.pi)
#define PAY56 0x00FFFFFFFFFFFFFFull

typedef float v2f __attribute__((ext_vector_type(2)));

// Static device scratch (rewritten every call before use)
__device__ float g_px[BATCH*NPTS];   // only group j=7 regions used
__device__ float g_py[BATCH*NPTS];
__device__ float g_pz[BATCH*NPTS];
__device__ float g_samp[BATCH*KSAMP*3];
__device__ float g_enc[(size_t)BATCH*KSAMP*INDIM];
__device__ float g_Wt[INDIM*HID];
// ONE tagged u64 per [parity][slice] (round-4/5 lesson: fat multi-word slots
// explode HBM traffic 150x; the whole batch's slots must stay in one line)
__device__ unsigned long long g_slot[BATCH][2][NBLK_PER_B];

__device__ __forceinline__ float san(float v){
  float m = v*0.0f;                 // finite -> 0, inf/nan -> nan (no fast-math fold)
  return (m == 0.0f) ? v : 0.0f;
}

__device__ __forceinline__ unsigned long long shfl64_xor(unsigned long long v, int m){
  unsigned lo = __shfl_xor((unsigned)v, m);
  unsigned hi = __shfl_xor((unsigned)(v>>32), m);
  return ((unsigned long long)hi<<32)|lo;
}
__device__ __forceinline__ unsigned long long shfl64(unsigned long long v, int src){
  unsigned lo = __shfl((unsigned)v, src);
  unsigned hi = __shfl((unsigned)(v>>32), src);
  return ((unsigned long long)hi<<32)|lo;
}

// ---------------- region prepass: sanitize + SoA for global-resident 1/8 ----------------
__global__ __launch_bounds__(256) void region_prepass(const float* __restrict__ pc){
  int bid = blockIdx.x;             // 1024 blocks
  int b   = bid >> 5;               // 32 blocks per batch
  int rem = bid & 31;
  int q   = rem*1024 + threadIdx.x*4;   // 0..32767 region-local (per batch)
  int s   = q >> 12;                    // slice (4096 pts of group 7 per slice)
  int o   = q & 4095;
  int p   = s*SLICE + 7*4096 + o;       // global point index in batch
  const float* src = pc + ((size_t)b*NPTS + p)*3;
  float4 A = *(const float4*)(src);
  float4 Bv= *(const float4*)(src+4);
  float4 C = *(const float4*)(src+8);
  float v[12] = {A.x,A.y,A.z,A.w,Bv.x,Bv.y,Bv.z,Bv.w,C.x,C.y,C.z,C.w};
#pragma unroll
  for (int j=0;j<12;j++) v[j] = san(v[j]);
  size_t base = (size_t)b*NPTS + p;
  *(float4*)(g_px+base) = make_float4(v[0],v[3],v[6],v[9]);
  *(float4*)(g_py+base) = make_float4(v[1],v[4],v[7],v[10]);
  *(float4*)(g_pz+base) = make_float4(v[2],v[5],v[8],v[11]);
}

// ---------------- W transpose + slot clear ----------------
__global__ __launch_bounds__(256) void wtrans(const float* __restrict__ W){
  int idx = blockIdx.x*256 + threadIdx.x;   // < 60*768 = 46080
  int d = idx / HID;
  int h = idx - d*HID;
  g_Wt[idx] = W[h*INDIM + d];
  if (blockIdx.x == 0 && threadIdx.x < 256){
    // clear all 32*2*8 = 512 slot words (stale tags could alias tag==k)
    ((unsigned long long*)g_slot)[threadIdx.x*2+0] = 0ull;
    ((unsigned long long*)g_slot)[threadIdx.x*2+1] = 0ull;
  }
}

// ---------------- FPS ----------------
__global__ __attribute__((amdgpu_flat_work_group_size(1024,1024)))
           __attribute__((amdgpu_waves_per_eu(4,4)))
void fps_kernel(const float* __restrict__ pc){
#pragma clang fp contract(off)
  // contract(off): distance chain must stay mul+add (rn each step, no FMA
  // fusion) to be bit-exact vs the reference reduction.
  __shared__ float4 sX[LDS_G*1024], sY[LDS_G*1024], sZ[LDS_G*1024];  // 144 KB
  __shared__ unsigned long long s_cand[16];  // per-wave candidate (barrier-ordered)
  __shared__ float s_res[4];                 // winner coords (barrier-ordered)

  // XCD-locality swizzle: assuming round-robin blockIdx%8 -> XCD, this puts
  // all 8 slices of a batch on ONE XCD (4 batches per XCD). Perf-only heuristic.
  const int blk = blockIdx.x;
  const int b   = (blk & 7) + 8*(blk >> 6);   // batch
  const int s   = (blk >> 3) & 7;             // slice
  const int tid = threadIdx.x;
  const int lane = tid & 63, wave = tid >> 6;
  const size_t bN = (size_t)b*NPTS;
  const int soff = s*SLICE;

  // ---- one-time load: regs (j=0..3, packed pairs) and LDS (j=4..6) ----
  v2f rx2[REG_G*2], ry2[REG_G*2], rz2[REG_G*2];   // pair p covers pts 2p,2p+1
#pragma unroll
  for (int j=0;j<REG_G+LDS_G;j++){
    int p0 = soff + j*4096 + tid*4;
    const float* src = pc + (bN + p0)*3;
    float4 A = *(const float4*)(src);
    float4 Bv= *(const float4*)(src+4);
    float4 C = *(const float4*)(src+8);
    float v[12] = {A.x,A.y,A.z,A.w,Bv.x,Bv.y,Bv.z,Bv.w,C.x,C.y,C.z,C.w};
#pragma unroll
    for (int q=0;q<12;q++) v[q] = san(v[q]);
    if (j < REG_G){
      rx2[j*2+0] = (v2f){v[0], v[3]};  rx2[j*2+1] = (v2f){v[6], v[9]};
      ry2[j*2+0] = (v2f){v[1], v[4]};  ry2[j*2+1] = (v2f){v[7], v[10]};
      rz2[j*2+0] = (v2f){v[2], v[5]};  rz2[j*2+1] = (v2f){v[8], v[11]};
    } else {
      sX[(j-REG_G)*1024+tid] = make_float4(v[0],v[3],v[6],v[9]);
      sY[(j-REG_G)*1024+tid] = make_float4(v[1],v[4],v[7],v[10]);
      sZ[(j-REG_G)*1024+tid] = make_float4(v[2],v[5],v[8],v[11]);
    }
  }

  float d[32];
#pragma unroll
  for (int i=0;i<32;i++) d[i] = __builtin_huge_valf();

  // first sample = sanitized point 0 (uniform scalar loads)
  float lx = san(pc[bN*3+0]), ly = san(pc[bN*3+1]), lz = san(pc[bN*3+2]);
  if (s==0 && tid<3) g_samp[(size_t)b*KSAMP*3 + tid] = san(pc[bN*3 + tid]);
  __syncthreads();   // LDS coords visible

  const size_t gb = bN + soff + (size_t)7*4096 + tid*4;   // loop-invariant

  for (int k=1; k<KSAMP; k++){
    const int par = k & 1;
    const unsigned long long tagk = (unsigned long long)(unsigned)k << 56;
    // issue global-group loads first (L2-resident region)
    float4 gx = *(const float4*)(g_px+gb);
    float4 gy = *(const float4*)(g_py+gb);
    float4 gz = *(const float4*)(g_pz+gb);

    // broadcast last sample into packed form
    v2f l2x = (v2f){lx,lx}, l2y = (v2f){ly,ly}, l2z = (v2f){lz,lz};

    float bestv = -1.0f; int bestc = 0;   // 5-bit slot code

    // packed distance for a PAIR of points (codes DI, DI+1); scalar tracking in
    // ascending index order preserves the first-max tie-break. pk ops are IEEE
    // rn per half == bit-exact vs the scalar __f*_rn chain.
#define UPD2(X2,Y2,Z2, DI) { \
      v2f dx_ = (X2) - l2x, dy_ = (Y2) - l2y, dz_ = (Z2) - l2z; \
      v2f dd_ = ((dx_*dx_) + (dy_*dy_)) + (dz_*dz_); \
      float nd0_ = fminf(d[DI], dd_.x);  d[DI] = nd0_; \
      if (nd0_ > bestv){ bestv = nd0_; bestc = (DI); } \
      float nd1_ = fminf(d[(DI)+1], dd_.y);  d[(DI)+1] = nd1_; \
      if (nd1_ > bestv){ bestv = nd1_; bestc = (DI)+1; } }

    // register groups j=0..3 (codes 0..15)
#pragma unroll
    for (int p=0;p<REG_G*2;p++)
      UPD2(rx2[p], ry2[p], rz2[p], p*2)
    // LDS groups j=4..6 (codes 16..27)
#pragma unroll
    for (int j=0;j<LDS_G;j++){
      float4 X = sX[j*1024+tid], Y = sY[j*1024+tid], Z = sZ[j*1024+tid];
      v2f Xa=(v2f){X.x,X.y}, Xb=(v2f){X.z,X.w};
      v2f Ya=(v2f){Y.x,Y.y}, Yb=(v2f){Y.z,Y.w};
      v2f Za=(v2f){Z.x,Z.y}, Zb=(v2f){Z.z,Z.w};
      UPD2(Xa, Ya, Za, (REG_G+j)*4)
      UPD2(Xb, Yb, Zb, (REG_G+j)*4+2)
    }
    // global group j=7 (codes 28..31)
    {
      v2f Xa=(v2f){gx.x,gx.y}, Xb=(v2f){gx.z,gx.w};
      v2f Ya=(v2f){gy.x,gy.y}, Yb=(v2f){gy.z,gy.w};
      v2f Za=(v2f){gz.x,gz.y}, Zb=(v2f){gz.z,gz.w};
      UPD2(Xa, Ya, Za, 28)
      UPD2(Xb, Yb, Zb, 30)
    }
#undef UPD2

    // code -> batch-local index (scan order was ascending-index so the
    // first-max tie-break is preserved)
    int besti = soff + ((bestc>>2)<<12) + (tid<<2) + (bestc&3);

    // intra-wave argmax (first-index tie-break)
#pragma unroll
    for (int off=32; off; off>>=1){
      float ov = __shfl_down(bestv, off);
      int   oi = __shfl_down(besti, off);
      if (ov > bestv || (ov == bestv && oi < besti)){ bestv=ov; besti=oi; }
    }
    // key: [val:32][0xFFFFFF^idx:24] — u64 max == (max val, then smallest idx)
    if (lane==0)
      s_cand[wave] = ((unsigned long long)__float_as_uint(bestv) << 24)
                   | (unsigned long long)(0xFFFFFFu ^ (unsigned)besti);

    // barrier #1: orders all 16 candidate stores before wave0's gather; the
    // 15 follower waves fall through to barrier #2 and park there (no spin,
    // no sleep quantization, zero issue pressure on wave0's serial section).
    __syncthreads();

    if (wave==0){
      // gather 16 wave candidates (plain LDS loads, barrier-ordered)
      unsigned long long pay = (lane < 16) ? s_cand[lane] : 0ull;
#pragma unroll
      for (int m=1; m<16; m<<=1){
        unsigned long long o = shfl64_xor(pay, m);
        if (o > pay) pay = o;
      }
      // publish block candidate (1 tagged word — the cheap protocol)
      if (lane==0)
        __hip_atomic_store(&g_slot[b][par][s], tagk | pay,
                           __ATOMIC_RELAXED, __HIP_MEMORY_SCOPE_AGENT);
      // tight-poll the 8 slices' slots (lane q watches slice q). No s_sleep:
      // one wave's poll is self-throttled by load latency, and the other 15
      // waves are parked at the barrier — issue slots are free.
      unsigned long long gpay = 0;
      if (lane < NBLK_PER_B){
        unsigned long long gv;
        for (;;){
          gv = __hip_atomic_load(&g_slot[b][par][lane],
                                 __ATOMIC_RELAXED, __HIP_MEMORY_SCOPE_AGENT);
          if ((unsigned)(gv >> 56) == (unsigned)k) break;
        }
        gpay = gv & PAY56;
      }
#pragma unroll
      for (int m=1; m<8; m<<=1){
        unsigned long long o = shfl64_xor(gpay, m);
        if (o > gpay) gpay = o;
      }
      unsigned long long wing = shfl64(gpay, 0);
      unsigned w = 0xFFFFFFu ^ (unsigned)(wing & 0xFFFFFFu);   // batch-local idx
      int wu = __builtin_amdgcn_readfirstlane((int)w);         // uniform -> scalar
      if (lane < 3){
        float cv = san(pc[(bN + (size_t)(unsigned)wu)*3 + lane]);
        s_res[lane] = cv;
        if (s==0) g_samp[((size_t)b*KSAMP + k)*3 + lane] = cv;
      }
    }

    // barrier #2: HW wake (no flag discovery latency); s_res visible after.
    __syncthreads();
    lx = s_res[0]; ly = s_res[1]; lz = s_res[2];
  }
}

// ---------------- normalize + Fourier encode ----------------
template<int OP>  // 0 sum, 1 max, 2 min
__device__ __forceinline__ float blk_red(float v, float* s4){
  int tid = threadIdx.x;
#pragma unroll
  for (int off=32; off; off>>=1){
    float o = __shfl_down(v, off);
    v = (OP==0) ? v+o : ((OP==1) ? fmaxf(v,o) : fminf(v,o));
  }
  if ((tid&63)==0) s4[tid>>6] = v;
  __syncthreads();
  float r0=s4[0], r1=s4[1], r2=s4[2], r3=s4[3];
  float r = (OP==0) ? ((r0+r1)+(r2+r3))
          : ((OP==1) ? fmaxf(fmaxf(r0,r1),fmaxf(r2,r3))
                     : fminf(fminf(r0,r1),fminf(r2,r3)));
  __syncthreads();
  return r;
}

__global__ __launch_bounds__(256) void norm_encode(){
  __shared__ float s4[4];
  int b = blockIdx.x, k = threadIdx.x;
  const float* sp = &g_samp[((size_t)b*KSAMP + k)*3];
  float x = sp[0], y = sp[1], z = sp[2];

  float cx = blk_red<0>(x, s4) * (1.0f/KSAMP);
  float cy = blk_red<0>(y, s4) * (1.0f/KSAMP);
  float cz = blk_red<0>(z, s4) * (1.0f/KSAMP);

  float ux = __fsub_rn(x,cx), uy = __fsub_rn(y,cy), uz = __fsub_rn(z,cz);

  float mxx = blk_red<1>(ux, s4), mnx = blk_red<2>(ux, s4);
  float mxy = blk_red<1>(uy, s4), mny = blk_red<2>(uy, s4);
  float mxz = blk_red<1>(uz, s4), mnz = blk_red<2>(uz, s4);
  float bx = __fsub_rn(mxx,mnx), by = __fsub_rn(mxy,mny), bz = __fsub_rn(mxz,mnz);
  float md = fmaxf(fmaxf(bx,by),bz);
  float scale = (md > 1e-8f) ? md : 1.0f;

  float n3[3] = { __fdiv_rn(ux,scale), __fdiv_rn(uy,scale), __fdiv_rn(uz,scale) };

  float* e = &g_enc[((size_t)b*KSAMP + k)*INDIM];
#pragma unroll
  for (int c=0;c<3;c++){
    float base = n3[c];
#pragma unroll
    for (int f=0; f<NF; f++){
      float t = __fmul_rn(base, (float)(1<<f));
      float a = __fmul_rn(t, PI_F);
      e[c*2*NF + f*2 + 0] = sinf(a);
      e[c*2*NF + f*2 + 1] = cosf(a);
    }
  }
}

// ---------------- GEMM ----------------
__global__ __launch_bounds__(256) void gemm_kernel(const float* __restrict__ bias,
                                                   float* __restrict__ out){
  __shared__ float s_enc[4*INDIM];
  int blk = blockIdx.x, tid = threadIdx.x;
  int row0 = blk*4;                         // 4 (b,k) rows per block
  if (tid < 4*INDIM) s_enc[tid] = g_enc[(size_t)row0*INDIM + tid];
  __syncthreads();

  float acc[4][3] = {};
  for (int d=0; d<INDIM; d++){
    float w0 = g_Wt[d*HID + tid];
    float w1 = g_Wt[d*HID + tid + 256];
    float w2 = g_Wt[d*HID + tid + 512];
#pragma unroll
    for (int r=0;r<4;r++){
      float ev = s_enc[r*INDIM + d];
      acc[r][0] = fmaf(ev, w0, acc[r][0]);
      acc[r][1] = fmaf(ev, w1, acc[r][1]);
      acc[r][2] = fmaf(ev, w2, acc[r][2]);
    }
  }
  float b0=bias[tid], b1=bias[tid+256], b2=bias[tid+512];
#pragma unroll
  for (int r=0;r<4;r++){
    size_t o = (size_t)(row0+r)*HID;
    out[o+tid]     = acc[r][0]+b0;
    out[o+tid+256] = acc[r][1]+b1;
    out[o+tid+512] = acc[r][2]+b2;
  }
}

// ---------------- launch ----------------
extern "C" void kernel_launch(void* const* d_in, const int* in_sizes, int n_in,
                              void* d_out, int out_size, void* d_ws, size_t ws_size,
                              hipStream_t stream){
  const float* pc   = (const float*)d_in[0];
  const float* W    = (const float*)d_in[1];
  const float* bias = (const float*)d_in[2];
  float* out = (float*)d_out;

  region_prepass<<<1024, 256, 0, stream>>>(pc);
  wtrans        <<<(INDIM*HID)/256, 256, 0, stream>>>(W);

  void* args[] = { (void*)&pc };
  hipLaunchCooperativeKernel((void*)fps_kernel, dim3(BATCH*NBLK_PER_B), dim3(1024),
                             args, 0, stream);

  norm_encode<<<BATCH, KSAMP, 0, stream>>>();
  gemm_kernel<<<(BATCH*KSAMP)/4, 256, 0, stream>>>(bias, out);
}